// Round 7
// baseline (122.819 us; speedup 1.0000x reference)
//
#include <hip/hip_runtime.h>
#include <math.h>

#define NCOL 32
#define DDIM 512
#define NPAIR 16
#define CATS 10
#define ROWS 32                    /* rows per wave */
#define ROW_STRIDE (NCOL * DDIM)   /* 16384 floats between consecutive b rows */

// v += dpp_permuted(v). old=0 / bound_ctrl=false: masked-off rows contribute 0.
template <int CTRL, int ROW_MASK>
__device__ __forceinline__ float dpp_add(float v) {
    int t = __builtin_amdgcn_update_dpp(0, __float_as_int(v), CTRL, ROW_MASK, 0xf, false);
    return v + __int_as_float(t);
}
// pure DPP move: returns permuted value (0 in masked-off rows).
template <int CTRL, int ROW_MASK>
__device__ __forceinline__ float dpp_mov(float v) {
    int t = __builtin_amdgcn_update_dpp(0, __float_as_int(v), CTRL, ROW_MASK, 0xf, false);
    return __int_as_float(t);
}

// After this: lane31 = sum(lanes 0..31), lane63 = sum(lanes 32..63). VALU only.
__device__ __forceinline__ float wave_reduce_halves(float v) {
    v = dpp_add<0x111, 0xf>(v);  // row_shr:1
    v = dpp_add<0x112, 0xf>(v);  // row_shr:2
    v = dpp_add<0x114, 0xf>(v);  // row_shr:4
    v = dpp_add<0x118, 0xf>(v);  // row_shr:8  -> lane15 of each row16 = row sum
    v = dpp_add<0x142, 0xa>(v);  // row_bcast:15 -> lane31, lane63 hold half-sums
    return v;
}
// Full 64-lane sum, valid in lane 63.
__device__ __forceinline__ float wave_reduce_full(float v) {
    v = wave_reduce_halves(v);
    v = dpp_add<0x143, 0xc>(v);  // row_bcast:31 into rows 2,3 -> lane63 = total
    return v;
}

// counted vmcnt wait; "memory" clobber pins all memory ops (ds_read included)
#define WAITVM(n) asm volatile("s_waitcnt vmcnt(" #n ")" ::: "memory")

// stage one pair-row (4 KiB) HBM -> wave-private LDS slot, 4 x 1KiB, no VGPRs
#define ISSUE(row, slot) do {                                                  \
    const float* _g = xb + (size_t)(row) * ROW_STRIDE;                         \
    float* _l = &slab[wslot][slot][0];                                         \
    _Pragma("unroll")                                                          \
    for (int _k = 0; _k < 4; ++_k)                                             \
        __builtin_amdgcn_global_load_lds(                                      \
            (const __attribute__((address_space(1))) unsigned int*)            \
                (_g + _k * 256 + lane * 4),                                    \
            (__attribute__((address_space(3))) unsigned int*)(_l + _k * 256),  \
            16, 0, 0);                                                         \
} while (0)

// consume one staged row: math byte-identical to the R6 (passing) kernel
#define PROC(slot, idx) do {                                                   \
    const float* pb = &slab[wslot][slot][0];                                   \
    float4 Ea = *(const float4*)(pb +   0 + 4 * lane);                         \
    float4 Eb = *(const float4*)(pb + 256 + 4 * lane);                         \
    float4 Oa = *(const float4*)(pb + 512 + 4 * lane);                         \
    float4 Ob = *(const float4*)(pb + 768 + 4 * lane);                         \
    double best = -1.0e300;                                                    \
    int bi = 0;                                                                \
    _Pragma("unroll")                                                          \
    for (int c = 0; c < CATS; ++c) {                                           \
        float s = Oa.x * wc[c];                                                \
        s = fmaf(Oa.y, wc[10 + c], s);                                         \
        s = fmaf(Oa.z, wc[20 + c], s);                                         \
        s = fmaf(Oa.w, wc[30 + c], s);                                         \
        s = fmaf(Ob.x, wc[40 + c], s);                                         \
        s = fmaf(Ob.y, wc[50 + c], s);                                         \
        s = fmaf(Ob.z, wc[60 + c], s);                                         \
        s = fmaf(Ob.w, wc[70 + c], s);                                         \
        s = wave_reduce_halves(s);                                             \
        float slo = dpp_mov<0x143, 0xc>(s);                                    \
        double d = (double)s + (double)slo + biasd[c];                         \
        if (d > best) { best = d; bi = c; }                                    \
    }                                                                          \
    float sn = Ea.x * w[0];                                                    \
    sn = fmaf(Ea.y, w[1], sn);                                                 \
    sn = fmaf(Ea.z, w[2], sn);                                                 \
    sn = fmaf(Ea.w, w[3], sn);                                                 \
    sn = fmaf(Eb.x, w[4], sn);                                                 \
    sn = fmaf(Eb.y, w[5], sn);                                                 \
    sn = fmaf(Eb.z, w[6], sn);                                                 \
    sn = fmaf(Eb.w, w[7], sn);                                                 \
    sn = wave_reduce_full(sn);                                                 \
    if (lane == 63) {                                                          \
        float2 o2 = make_float2(tanhf(sn + bias), (float)bi);                  \
        *(float2*)(ob + (size_t)(idx) * NCOL) = o2;                            \
    }                                                                          \
} while (0)

__global__ __launch_bounds__(256, 3) void pair_ring_kernel(
    const float* __restrict__ x,
    const float* __restrict__ Wn,
    const float* __restrict__ bn,
    const float* __restrict__ Wc,
    const float* __restrict__ bc,
    float* __restrict__ out)
{
    // wave-private triple-buffered slabs: 4 waves x 3 slots x 4 KiB = 48 KiB
    __shared__ float slab[4][3][1024];

    const int lane  = threadIdx.x & 63;
    const int wslot = threadIdx.x >> 6;
    const int wid   = __builtin_amdgcn_readfirstlane(blockIdx.x * 4 + wslot); // 0..4095
    const int p     = wid & (NPAIR - 1);   // block's 4 waves = 4 consecutive pairs
    const int chunk = wid >> 4;            // 0..255
    const size_t b0 = (size_t)chunk * ROWS;

    // ---- numeric weights (per-lane slice of Wn[p]) — identical to R6
    float w[8];
    {
        float4 wa = *(const float4*)(Wn + p * DDIM + lane * 4);
        float4 wb = *(const float4*)(Wn + p * DDIM + 256 + lane * 4);
        w[0]=wa.x; w[1]=wa.y; w[2]=wa.z; w[3]=wa.w;
        w[4]=wb.x; w[5]=wb.y; w[6]=wb.z; w[7]=wb.w;
    }
    const float bias = __int_as_float(
        __builtin_amdgcn_readfirstlane(__float_as_int(bn[p])));

    // ---- categorical weights: wc[dd*10+c] low half, wc[40+dd*10+c] high half
    float wc[80];
    {
        const float* w0 = Wc + ((size_t)p * DDIM + lane * 4) * CATS;
        const float* w1 = Wc + ((size_t)p * DDIM + 256 + lane * 4) * CATS;
        #pragma unroll
        for (int k = 0; k < 10; ++k) {
            float4 t = *(const float4*)(w0 + k * 4);
            wc[4*k] = t.x; wc[4*k+1] = t.y; wc[4*k+2] = t.z; wc[4*k+3] = t.w;
        }
        #pragma unroll
        for (int k = 0; k < 10; ++k) {
            float4 t = *(const float4*)(w1 + k * 4);
            wc[40+4*k] = t.x; wc[40+4*k+1] = t.y; wc[40+4*k+2] = t.z; wc[40+4*k+3] = t.w;
        }
    }
    double biasd[CATS];  // wave-uniform -> SGPR pairs (as in passing R6)
    #pragma unroll
    for (int c = 0; c < CATS; ++c)
        biasd[c] = (double)__int_as_float(
            __builtin_amdgcn_readfirstlane(__float_as_int(bc[p * CATS + c])));

    // this wave's pair data: 1024 contiguous floats per row (even+odd cols)
    const float* xb = x + b0 * ROW_STRIDE + (size_t)(2 * p) * DDIM;
    float* ob = out + b0 * NCOL + 2 * p;

    // ---- barrier-free ring pipeline, 2 rows ahead, vmcnt never drained to 0.
    // issue order: L0 L1 | [S0 L2] [S1 L3] ... ; at top of iter r the ops
    // newer than L_r are {S_{r-1}, L_{r+1}} = 5  ->  s_waitcnt vmcnt(5).
    ISSUE(0, 0);
    ISSUE(1, 1);

    // iter 0: only L1 (4 ops) newer than L0
    WAITVM(4);
    PROC(0, 0);
    ISSUE(2, 2);

    #pragma unroll 3
    for (int r = 1; r <= ROWS - 2; ++r) {
        WAITVM(5);
        const int slot = r % 3;
        PROC(slot, r);
        if (r + 2 < ROWS) ISSUE(r + 2, (r + 2) % 3);
    }

    // final row: only S_{ROWS-2} (1 op) newer than its loads
    WAITVM(1);
    PROC((ROWS - 1) % 3, ROWS - 1);
}

extern "C" void kernel_launch(void* const* d_in, const int* in_sizes, int n_in,
                              void* d_out, int out_size, void* d_ws, size_t ws_size,
                              hipStream_t stream) {
    const float* x  = (const float*)d_in[0];
    const float* Wn = (const float*)d_in[1];
    const float* bn = (const float*)d_in[2];
    const float* Wc = (const float*)d_in[3];
    const float* bc = (const float*)d_in[4];
    float* out = (float*)d_out;

    // 4096 waves: (pair 0..15) x (32-row chunk 0..255); 4 consecutive pairs
    // per block -> 16 KiB contiguous DRAM footprint per block per row.
    hipLaunchKernelGGL(pair_ring_kernel, dim3(1024), dim3(256), 0, stream,
                       x, Wn, bn, Wc, bc, out);
}